// Round 2
// baseline (337.705 us; speedup 1.0000x reference)
//
#include <hip/hip_runtime.h>

typedef unsigned short u16;
typedef unsigned int u32;
typedef __bf16 bf16x8 __attribute__((ext_vector_type(8)));
typedef float f32x4 __attribute__((ext_vector_type(4)));
typedef u16 u16x8 __attribute__((ext_vector_type(8)));

// B=8, N=512, D=512, H=8, DH=64, E=32768, BIAS_DIM=8
// M = B*N = 4096; all GEMMs are M x 512 x 512.
// ALL float tensors are float32 (per harness contract). MFMA operands are
// rounded to bf16 (RNE); accumulation f32; intermediates f32.

__device__ __forceinline__ u16 f2b(float f) {
  union { float f; u32 i; } v; v.f = f;
  u32 r = v.i + 0x7fffu + ((v.i >> 16) & 1u);
  return (u16)(r >> 16);
}

// ---------- 512x512 transpose + f32->bf16 for the 4 weight matrices ----------
__global__ void transpose_w(const float* __restrict__ w0, const float* __restrict__ w1,
                            const float* __restrict__ w2, const float* __restrict__ w3,
                            u16* __restrict__ o0, u16* __restrict__ o1,
                            u16* __restrict__ o2, u16* __restrict__ o3) {
  __shared__ u16 t[32][33];
  const float* src; u16* dst;
  if (blockIdx.z == 0)      { src = w0; dst = o0; }
  else if (blockIdx.z == 1) { src = w1; dst = o1; }
  else if (blockIdx.z == 2) { src = w2; dst = o2; }
  else                      { src = w3; dst = o3; }
  int tx = threadIdx.x, ty = threadIdx.y;
  int c0 = blockIdx.x * 32, r0 = blockIdx.y * 32;
  #pragma unroll
  for (int i = ty; i < 32; i += 8) t[i][tx] = f2b(src[(r0 + i) * 512 + c0 + tx]);
  __syncthreads();
  #pragma unroll
  for (int i = ty; i < 32; i += 8) dst[(c0 + i) * 512 + r0 + tx] = t[tx][i];
}

// ---------- batched 512x512 f32 transpose: k (b,t,h*64+a) -> kt (b, h*64+a, t) ----------
__global__ void transpose_k(const float* __restrict__ in, float* __restrict__ out) {
  __shared__ float t[32][33];
  size_t base = (size_t)blockIdx.z * 262144;
  const float* src = in + base;
  float* dst = out + base;
  int tx = threadIdx.x, ty = threadIdx.y;
  int c0 = blockIdx.x * 32, r0 = blockIdx.y * 32;
  #pragma unroll
  for (int i = ty; i < 32; i += 8) t[i][tx] = src[(r0 + i) * 512 + c0 + tx];
  __syncthreads();
  #pragma unroll
  for (int i = ty; i < 32; i += 8) dst[(c0 + i) * 512 + r0 + tx] = t[tx][i];
}

// ---------- edge-bias scatter: bias_mat[b,q,k] += dot(bias_embs[et], bias_scalar) ----------
__global__ void scatter_bias(const int* __restrict__ ab, const float* __restrict__ be,
                             const float* __restrict__ bsc, float* __restrict__ bias_mat,
                             int n_edges) {
  __shared__ float tv[8];
  int tid = threadIdx.x;
  if (tid < 8) {
    float s = 0.f;
    #pragma unroll
    for (int a = 0; a < 64; a++) s += be[tid * 64 + a] * bsc[a];
    tv[tid] = s;
  }
  __syncthreads();
  int e = blockIdx.x * 256 + tid;
  if (e < n_edges) {
    int et = ab[e * 4 + 0];
    int b  = ab[e * 4 + 1];
    int qi = ab[e * 4 + 2];
    int ki = ab[e * 4 + 3];
    atomicAdd(&bias_mat[((size_t)b * 512 + qi) * 512 + ki], tv[et]);
  }
}

// ---------- MFMA GEMM: C[m][n] = sum_k A[m][k]*BT[n][k]; A f32, BT bf16, C f32 ----------
// 64x64 tile, 4 waves (2x2 of 32x32), 16x16x32 MFMA, K-chunks of 32.
// A converted f32->bf16 inline during staging. LDS stride 40 elems = 80B (2-way
// bank aliasing only, free per m136).
__global__ __launch_bounds__(256) void gemm_bt(const float* __restrict__ A,
                                               const u16* __restrict__ BT,
                                               float* __restrict__ C) {
  __shared__ u16 As[64 * 40];
  __shared__ u16 Bs[64 * 40];
  const int K = 512;
  int tid = threadIdx.x;
  int lane = tid & 63;
  int wave = tid >> 6;
  int quad = lane >> 4, ln = lane & 15;
  int wr = wave >> 1, wc = wave & 1;
  int row0 = blockIdx.x * 64;
  int col0 = blockIdx.y * 64;
  int lr = tid >> 2;          // staging row 0..63
  int lc = (tid & 3) * 8;     // staging col group (8 elems)
  f32x4 acc[2][2];
  #pragma unroll
  for (int i = 0; i < 2; i++)
    #pragma unroll
    for (int j = 0; j < 2; j++)
      acc[i][j] = (f32x4){0.f, 0.f, 0.f, 0.f};

  const float* aptr = A + (size_t)(row0 + lr) * K + lc;
  const float4* bp = (const float4*)&BT[(size_t)(col0 + lr) * K + lc];

  for (int k0 = 0; k0 < K; k0 += 32) {
    float4 x = *(const float4*)(aptr + k0);
    float4 y = *(const float4*)(aptr + k0 + 4);
    float4 bv = bp[k0 >> 3];
    u16x8 pk;
    pk[0] = f2b(x.x); pk[1] = f2b(x.y); pk[2] = f2b(x.z); pk[3] = f2b(x.w);
    pk[4] = f2b(y.x); pk[5] = f2b(y.y); pk[6] = f2b(y.z); pk[7] = f2b(y.w);
    __syncthreads();           // protect previous iteration's LDS reads
    *(u16x8*)&As[lr * 40 + lc] = pk;
    *(float4*)&Bs[lr * 40 + lc] = bv;
    __syncthreads();
    #pragma unroll
    for (int i = 0; i < 2; i++) {
      bf16x8 af = *(bf16x8*)&As[(wr * 32 + i * 16 + ln) * 40 + quad * 8];
      #pragma unroll
      for (int j = 0; j < 2; j++) {
        bf16x8 bfr = *(bf16x8*)&Bs[(wc * 32 + j * 16 + ln) * 40 + quad * 8];
        acc[i][j] = __builtin_amdgcn_mfma_f32_16x16x32_bf16(af, bfr, acc[i][j], 0, 0, 0);
      }
    }
  }
  #pragma unroll
  for (int i = 0; i < 2; i++)
    #pragma unroll
    for (int j = 0; j < 2; j++) {
      int mb = row0 + wr * 32 + i * 16 + quad * 4;
      int n = col0 + wc * 32 + j * 16 + ln;
      #pragma unroll
      for (int r = 0; r < 4; r++)
        C[(size_t)(mb + r) * 512 + n] = acc[i][j][r];
    }
}

// ---------- summed_keys[b,t,h] = sum_a k[b,t,h,a], read from kt (bh, a, t) ----------
__global__ void sumk_kernel(const float* __restrict__ kt, float* __restrict__ summed) {
  int tid = blockIdx.x * 256 + threadIdx.x;  // 0..32767
  int t = tid & 511, bh = tid >> 9;
  float s = 0.f;
  #pragma unroll 8
  for (int a = 0; a < 64; a++) s += kt[((size_t)bh * 64 + a) * 512 + t];
  summed[((size_t)(bh >> 3) * 512 + t) * 8 + (bh & 7)] = s;
}

// ---------- attention: one wave per q row; scores row in LDS; softmax; PV ----------
__global__ __launch_bounds__(256) void attn_kernel(const float* __restrict__ q,
                                                   const float* __restrict__ k_t,
                                                   const float* __restrict__ v,
                                                   const float* __restrict__ masks,
                                                   const float* __restrict__ bias_mat,
                                                   const float* __restrict__ summed,
                                                   float* __restrict__ ctx) {
  __shared__ float qs[4][64];
  __shared__ float sc[4][512];
  int wave = threadIdx.x >> 6, lane = threadIdx.x & 63;
  int bh = blockIdx.x >> 7;            // 128 blocks per (b,h)
  int b = bh >> 3, h = bh & 7;
  int r = (blockIdx.x & 127) * 4 + wave;  // q row 0..511

  qs[wave][lane] = q[((size_t)(b * 512 + r)) * 512 + h * 64 + lane];

  int nkb = (r >> 6) + 1;              // key blocks with any unmasked key
  const float* kbase = k_t + (size_t)bh * 64 * 512;
  for (int kb = 0; kb < nkb; kb++) {
    int kk = kb * 64 + lane;
    float acc = 0.f;
    const float* kp = kbase + kk;
    #pragma unroll 8
    for (int a = 0; a < 64; a++) acc += qs[wave][a] * kp[(size_t)a * 512];
    float bm = bias_mat[((size_t)(b * 512 + r)) * 512 + kk];
    float sk = summed[((size_t)b * 512 + kk) * 8 + h];
    float m = masks[((size_t)b * 512 + r) * 512 + kk];
    float s = (acc + bm * sk) * 0.125f;
    s = s * m + (1.f - ceilf(m)) * (-3.40282347e38f);
    sc[wave][kk] = s;
  }
  // softmax over keys 0..nkb*64-1 (keys beyond r give exp(-huge)=0 exactly)
  int nk = nkb * 64;
  float mx = -3.40282347e38f;
  for (int kk = lane; kk < nk; kk += 64) mx = fmaxf(mx, sc[wave][kk]);
  #pragma unroll
  for (int o = 32; o; o >>= 1) mx = fmaxf(mx, __shfl_xor(mx, o));
  float sum = 0.f;
  for (int kk = lane; kk < nk; kk += 64) {
    float p = __expf(sc[wave][kk] - mx);
    sc[wave][kk] = p;
    sum += p;
  }
  #pragma unroll
  for (int o = 32; o; o >>= 1) sum += __shfl_xor(sum, o);
  float inv = 1.f / sum;
  // PV: lane = a
  float acc = 0.f;
  const float* vp = v + ((size_t)b * 512) * 512 + h * 64 + lane;
  #pragma unroll 4
  for (int kk = 0; kk <= r; kk++) acc += sc[wave][kk] * vp[(size_t)kk * 512];
  ctx[((size_t)(b * 512 + r)) * 512 + h * 64 + lane] = acc * inv;
}

extern "C" void kernel_launch(void* const* d_in, const int* in_sizes, int n_in,
                              void* d_out, int out_size, void* d_ws, size_t ws_size,
                              hipStream_t stream) {
  const float* states     = (const float*)d_in[0];
  const float* key_states = (const float*)d_in[1];
  const float* masks      = (const float*)d_in[2];
  const int*   ab         = (const int*)d_in[3];
  const float* Wq         = (const float*)d_in[4];
  const float* Wk         = (const float*)d_in[5];
  const float* Wv         = (const float*)d_in[6];
  const float* Wo         = (const float*)d_in[7];
  const float* be         = (const float*)d_in[8];
  const float* bsc        = (const float*)d_in[9];
  float* out = (float*)d_out;

  char* ws = (char*)d_ws;
  const size_t MB = 1024 * 1024;
  u16* wqt      = (u16*)(ws);                 // 512 KB bf16
  u16* wkt      = (u16*)(ws + 512 * 1024);    // 512 KB
  u16* wvt      = (u16*)(ws + 1024 * 1024);   // 512 KB
  u16* wot      = (u16*)(ws + 1536 * 1024);   // 512 KB
  float* qb     = (float*)(ws + 2 * MB);      // 8 MB f32 (4096x512)
  float* kb     = (float*)(ws + 10 * MB);     // 8 MB
  float* kt     = (float*)(ws + 18 * MB);     // 8 MB
  float* vb     = (float*)(ws + 26 * MB);     // 8 MB
  float* ctx    = (float*)(ws + 34 * MB);     // 8 MB
  float* bias_m = (float*)(ws + 42 * MB);     // 8 MB
  float* summed = (float*)(ws + 50 * MB);     // 128 KB

  int n_edges = in_sizes[3] / 4;

  hipMemsetAsync(bias_m, 0, (size_t)8 * MB, stream);
  transpose_w<<<dim3(16, 16, 4), dim3(32, 8), 0, stream>>>(Wq, Wk, Wv, Wo, wqt, wkt, wvt, wot);
  scatter_bias<<<dim3((n_edges + 255) / 256), 256, 0, stream>>>(ab, be, bsc, bias_m, n_edges);
  gemm_bt<<<dim3(64, 8), 256, 0, stream>>>(states, wqt, qb);
  gemm_bt<<<dim3(64, 8), 256, 0, stream>>>(key_states, wkt, kb);
  gemm_bt<<<dim3(64, 8), 256, 0, stream>>>(key_states, wvt, vb);
  transpose_k<<<dim3(16, 16, 8), dim3(32, 8), 0, stream>>>(kb, kt);
  sumk_kernel<<<dim3(128), 256, 0, stream>>>(kt, summed);
  attn_kernel<<<dim3(8192), 256, 0, stream>>>(qb, kt, vb, masks, bias_m, summed, ctx);
  gemm_bt<<<dim3(64, 8), 256, 0, stream>>>(ctx, wot, out);
}

// Round 3
// 174.861 us; speedup vs baseline: 1.9313x; 1.9313x over previous
//
#include <hip/hip_runtime.h>

typedef unsigned short u16;
typedef unsigned int u32;
typedef __bf16 bf16x8 __attribute__((ext_vector_type(8)));
typedef float f32x4 __attribute__((ext_vector_type(4)));
typedef u16 u16x8 __attribute__((ext_vector_type(8)));

// B=8, N=512, D=512, H=8, DH=64, E=32768, BIAS_DIM=8
// All float tensors are f32. MFMA operands rounded to bf16; accum f32.

__device__ __forceinline__ u16 f2b(float f) {
  union { float f; u32 i; } v; v.f = f;
  u32 r = v.i + 0x7fffu + ((v.i >> 16) & 1u);
  return (u16)(r >> 16);
}

// pack 16 consecutive f32 -> 16 bf16 into dst[0..15]
__device__ __forceinline__ void stage16(const float* __restrict__ src, u16* __restrict__ dst) {
  float4 x0 = ((const float4*)src)[0];
  float4 x1 = ((const float4*)src)[1];
  float4 x2 = ((const float4*)src)[2];
  float4 x3 = ((const float4*)src)[3];
  u16x8 p0, p1;
  p0[0] = f2b(x0.x); p0[1] = f2b(x0.y); p0[2] = f2b(x0.z); p0[3] = f2b(x0.w);
  p0[4] = f2b(x1.x); p0[5] = f2b(x1.y); p0[6] = f2b(x1.z); p0[7] = f2b(x1.w);
  p1[0] = f2b(x2.x); p1[1] = f2b(x2.y); p1[2] = f2b(x2.z); p1[3] = f2b(x2.w);
  p1[4] = f2b(x3.x); p1[5] = f2b(x3.y); p1[6] = f2b(x3.z); p1[7] = f2b(x3.w);
  *(u16x8*)dst = p0;
  *(u16x8*)(dst + 8) = p1;
}

// ---------- 512x512 transpose + f32->bf16 for the 4 weight matrices ----------
__global__ void transpose_w(const float* __restrict__ w0, const float* __restrict__ w1,
                            const float* __restrict__ w2, const float* __restrict__ w3,
                            u16* __restrict__ o0, u16* __restrict__ o1,
                            u16* __restrict__ o2, u16* __restrict__ o3) {
  __shared__ u16 t[32][33];
  const float* src; u16* dst;
  if (blockIdx.z == 0)      { src = w0; dst = o0; }
  else if (blockIdx.z == 1) { src = w1; dst = o1; }
  else if (blockIdx.z == 2) { src = w2; dst = o2; }
  else                      { src = w3; dst = o3; }
  int tx = threadIdx.x, ty = threadIdx.y;
  int c0 = blockIdx.x * 32, r0 = blockIdx.y * 32;
  #pragma unroll
  for (int i = ty; i < 32; i += 8) t[i][tx] = f2b(src[(r0 + i) * 512 + c0 + tx]);
  __syncthreads();
  #pragma unroll
  for (int i = ty; i < 32; i += 8) dst[(c0 + i) * 512 + r0 + tx] = t[tx][i];
}

// ---------- edge-bias scatter ----------
__global__ void scatter_bias(const int* __restrict__ ab, const float* __restrict__ be,
                             const float* __restrict__ bsc, float* __restrict__ bias_mat,
                             int n_edges) {
  __shared__ float tv[8];
  int tid = threadIdx.x;
  if (tid < 8) {
    float s = 0.f;
    #pragma unroll
    for (int a = 0; a < 64; a++) s += be[tid * 64 + a] * bsc[a];
    tv[tid] = s;
  }
  __syncthreads();
  int e = blockIdx.x * 256 + tid;
  if (e < n_edges) {
    int et = ab[e * 4 + 0];
    int b  = ab[e * 4 + 1];
    int qi = ab[e * 4 + 2];
    int ki = ab[e * 4 + 3];
    atomicAdd(&bias_mat[((size_t)b * 512 + qi) * 512 + ki], tv[et]);
  }
}

// ---------- MFMA GEMM: C[m][n] = sum_k A[m][k]*BT[n][k]; A f32, BT bf16, C f32 ----------
__global__ __launch_bounds__(256) void gemm_bt(const float* __restrict__ A,
                                               const u16* __restrict__ BT,
                                               float* __restrict__ C) {
  __shared__ u16 As[64 * 40];
  __shared__ u16 Bs[64 * 40];
  const int K = 512;
  int tid = threadIdx.x;
  int lane = tid & 63;
  int wave = tid >> 6;
  int quad = lane >> 4, ln = lane & 15;
  int wr = wave >> 1, wc = wave & 1;
  int row0 = blockIdx.x * 64;
  int col0 = blockIdx.y * 64;
  int lr = tid >> 2;
  int lc = (tid & 3) * 8;
  f32x4 acc[2][2];
  #pragma unroll
  for (int i = 0; i < 2; i++)
    #pragma unroll
    for (int j = 0; j < 2; j++)
      acc[i][j] = (f32x4){0.f, 0.f, 0.f, 0.f};

  const float* aptr = A + (size_t)(row0 + lr) * K + lc;
  const float4* bp = (const float4*)&BT[(size_t)(col0 + lr) * K + lc];

  for (int k0 = 0; k0 < K; k0 += 32) {
    float4 x = *(const float4*)(aptr + k0);
    float4 y = *(const float4*)(aptr + k0 + 4);
    float4 bv = bp[k0 >> 3];
    u16x8 pk;
    pk[0] = f2b(x.x); pk[1] = f2b(x.y); pk[2] = f2b(x.z); pk[3] = f2b(x.w);
    pk[4] = f2b(y.x); pk[5] = f2b(y.y); pk[6] = f2b(y.z); pk[7] = f2b(y.w);
    __syncthreads();
    *(u16x8*)&As[lr * 40 + lc] = pk;
    *(float4*)&Bs[lr * 40 + lc] = bv;
    __syncthreads();
    #pragma unroll
    for (int i = 0; i < 2; i++) {
      bf16x8 af = *(bf16x8*)&As[(wr * 32 + i * 16 + ln) * 40 + quad * 8];
      #pragma unroll
      for (int j = 0; j < 2; j++) {
        bf16x8 bfr = *(bf16x8*)&Bs[(wc * 32 + j * 16 + ln) * 40 + quad * 8];
        acc[i][j] = __builtin_amdgcn_mfma_f32_16x16x32_bf16(af, bfr, acc[i][j], 0, 0, 0);
      }
    }
  }
  #pragma unroll
  for (int i = 0; i < 2; i++)
    #pragma unroll
    for (int j = 0; j < 2; j++) {
      int mb = row0 + wr * 32 + i * 16 + quad * 4;
      int n = col0 + wc * 32 + j * 16 + ln;
      #pragma unroll
      for (int r = 0; r < 4; r++)
        C[(size_t)(mb + r) * 512 + n] = acc[i][j][r];
    }
}

// ---------- summed[bh*512+t] = sum_a k[b,t,h,a]; one wave per (b,h,t) ----------
__global__ void sumk2(const float* __restrict__ k, float* __restrict__ summed) {
  int tri = blockIdx.x * 4 + (threadIdx.x >> 6);  // 0..32767 = bh*512+t
  int lane = threadIdx.x & 63;
  int bh = tri >> 9, t = tri & 511;
  int b = bh >> 3, h = bh & 7;
  float x = k[((size_t)(b * 512 + t)) * 512 + h * 64 + lane];
  #pragma unroll
  for (int o = 32; o; o >>= 1) x += __shfl_xor(x, o);
  if (lane == 0) summed[tri] = x;
}

// ---------- MFMA flash attention ----------
// Block: one (b,h,q-tile of 64). 4 waves x 16 q-rows. Key tiles of 64, online softmax.
// Q from qb (q,a); K from kb (t,a) [= B^T for QK^T]; V staged transposed (a,t).
__global__ __launch_bounds__(256) void attn_mfma(const float* __restrict__ q,
                                                 const float* __restrict__ k,
                                                 const float* __restrict__ v,
                                                 const float* __restrict__ masks,
                                                 const float* __restrict__ bias_mat,
                                                 const float* __restrict__ summed,
                                                 float* __restrict__ ctx) {
  __shared__ u16 Qs[64 * 72];
  __shared__ u16 Ks[64 * 72];
  __shared__ u16 Vt[64 * 72];
  __shared__ u16 Ps[4][16 * 72];
  int tid = threadIdx.x;
  int wave = tid >> 6, lane = tid & 63;
  int quad = lane >> 4, ln = lane & 15;
  int blk = blockIdx.x;
  int qt = blk & 7, bh = blk >> 3;     // interleave q-tiles for load balance
  int b = bh >> 3, h = bh & 7;
  int q0 = qt * 64;

  // stage Q tile (64 rows x 64 a) as bf16
  {
    int lr = tid >> 2;
    int lc = (tid & 3) * 16;
    stage16(q + ((size_t)(b * 512 + q0 + lr)) * 512 + h * 64 + lc, &Qs[lr * 72 + lc]);
  }

  float m_r[4], l_r[4];
  f32x4 o[4];
  #pragma unroll
  for (int r = 0; r < 4; r++) { m_r[r] = -3.40282347e38f; l_r[r] = 0.f; }
  #pragma unroll
  for (int nt = 0; nt < 4; nt++) o[nt] = (f32x4){0.f, 0.f, 0.f, 0.f};

  for (int kb = 0; kb <= qt; kb++) {
    __syncthreads();   // protect previous iteration's LDS reads (also fences Q stage on iter 0)
    {
      int lr = tid >> 2;
      int lc = (tid & 3) * 16;
      stage16(k + ((size_t)(b * 512 + kb * 64 + lr)) * 512 + h * 64 + lc, &Ks[lr * 72 + lc]);
    }
    #pragma unroll
    for (int e = 0; e < 4; e++) {
      int idx = e * 256 + tid;               // 0..1023 float4 chunks
      int t = idx >> 4, a0 = (idx & 15) * 4;
      float4 x = *(const float4*)(v + ((size_t)(b * 512 + kb * 64 + t)) * 512 + h * 64 + a0);
      Vt[(a0 + 0) * 72 + t] = f2b(x.x);
      Vt[(a0 + 1) * 72 + t] = f2b(x.y);
      Vt[(a0 + 2) * 72 + t] = f2b(x.z);
      Vt[(a0 + 3) * 72 + t] = f2b(x.w);
    }
    __syncthreads();

    // S = Q K^T  (4 n-tiles of 16 cols, K-dim 64 in 2 steps)
    bf16x8 aq0 = *(bf16x8*)&Qs[(wave * 16 + ln) * 72 + quad * 8];
    bf16x8 aq1 = *(bf16x8*)&Qs[(wave * 16 + ln) * 72 + 32 + quad * 8];
    f32x4 s[4];
    #pragma unroll
    for (int nt = 0; nt < 4; nt++) {
      bf16x8 b0 = *(bf16x8*)&Ks[(nt * 16 + ln) * 72 + quad * 8];
      bf16x8 b1 = *(bf16x8*)&Ks[(nt * 16 + ln) * 72 + 32 + quad * 8];
      s[nt] = (f32x4){0.f, 0.f, 0.f, 0.f};
      s[nt] = __builtin_amdgcn_mfma_f32_16x16x32_bf16(aq0, b0, s[nt], 0, 0, 0);
      s[nt] = __builtin_amdgcn_mfma_f32_16x16x32_bf16(aq1, b1, s[nt], 0, 0, 0);
    }

    // bias + scale (+ exact mask formula on the diagonal tile only; sub-diagonal
    // tiles of a tril mask are all-ones)
    int qrow = q0 + wave * 16 + quad * 4;
    #pragma unroll
    for (int nt = 0; nt < 4; nt++) {
      int t = kb * 64 + nt * 16 + ln;
      float sk = summed[bh * 512 + t];
      const float* bp = bias_mat + ((size_t)(b * 512 + qrow)) * 512 + t;
      #pragma unroll
      for (int r = 0; r < 4; r++)
        s[nt][r] = (s[nt][r] + bp[(size_t)r * 512] * sk) * 0.125f;
      if (kb == qt) {
        const float* mp = masks + ((size_t)(b * 512 + qrow)) * 512 + t;
        #pragma unroll
        for (int r = 0; r < 4; r++) {
          float m = mp[(size_t)r * 512];
          s[nt][r] = s[nt][r] * m + (1.f - ceilf(m)) * (-3.40282347e38f);
        }
      }
    }

    // online softmax (rows live in quads: row = quad*4+reg; reduce over ln)
    float alpha[4];
    #pragma unroll
    for (int r = 0; r < 4; r++) {
      float tm = fmaxf(fmaxf(s[0][r], s[1][r]), fmaxf(s[2][r], s[3][r]));
      #pragma unroll
      for (int off = 8; off; off >>= 1) tm = fmaxf(tm, __shfl_xor(tm, off));
      float mn = fmaxf(m_r[r], tm);
      alpha[r] = __expf(m_r[r] - mn);
      m_r[r] = mn;
      float rs = 0.f;
      #pragma unroll
      for (int nt = 0; nt < 4; nt++) {
        float p = __expf(s[nt][r] - mn);
        s[nt][r] = p;
        rs += p;
      }
      #pragma unroll
      for (int off = 8; off; off >>= 1) rs += __shfl_xor(rs, off);
      l_r[r] = l_r[r] * alpha[r] + rs;
    }

    // P -> wave-private LDS (C-layout -> A-layout transpose), rescale O
    #pragma unroll
    for (int nt = 0; nt < 4; nt++)
      #pragma unroll
      for (int r = 0; r < 4; r++)
        Ps[wave][(quad * 4 + r) * 72 + nt * 16 + ln] = f2b(s[nt][r]);
    #pragma unroll
    for (int nt = 0; nt < 4; nt++)
      #pragma unroll
      for (int r = 0; r < 4; r++)
        o[nt][r] *= alpha[r];

    // O += P V   (wave-internal LDS dependency; lgkmcnt handles ordering)
    bf16x8 ap0 = *(bf16x8*)&Ps[wave][ln * 72 + quad * 8];
    bf16x8 ap1 = *(bf16x8*)&Ps[wave][ln * 72 + 32 + quad * 8];
    #pragma unroll
    for (int nt = 0; nt < 4; nt++) {
      bf16x8 b0 = *(bf16x8*)&Vt[(nt * 16 + ln) * 72 + quad * 8];
      bf16x8 b1 = *(bf16x8*)&Vt[(nt * 16 + ln) * 72 + 32 + quad * 8];
      o[nt] = __builtin_amdgcn_mfma_f32_16x16x32_bf16(ap0, b0, o[nt], 0, 0, 0);
      o[nt] = __builtin_amdgcn_mfma_f32_16x16x32_bf16(ap1, b1, o[nt], 0, 0, 0);
    }
  }

  // epilogue: normalize and store
  #pragma unroll
  for (int r = 0; r < 4; r++) {
    float inv = 1.f / l_r[r];
    int qrow = q0 + wave * 16 + quad * 4 + r;
    float* dst = ctx + ((size_t)(b * 512 + qrow)) * 512 + h * 64;
    #pragma unroll
    for (int nt = 0; nt < 4; nt++)
      dst[nt * 16 + ln] = o[nt][r] * inv;
  }
}

extern "C" void kernel_launch(void* const* d_in, const int* in_sizes, int n_in,
                              void* d_out, int out_size, void* d_ws, size_t ws_size,
                              hipStream_t stream) {
  const float* states     = (const float*)d_in[0];
  const float* key_states = (const float*)d_in[1];
  const float* masks      = (const float*)d_in[2];
  const int*   ab         = (const int*)d_in[3];
  const float* Wq         = (const float*)d_in[4];
  const float* Wk         = (const float*)d_in[5];
  const float* Wv         = (const float*)d_in[6];
  const float* Wo         = (const float*)d_in[7];
  const float* be         = (const float*)d_in[8];
  const float* bsc        = (const float*)d_in[9];
  float* out = (float*)d_out;

  char* ws = (char*)d_ws;
  const size_t MB = 1024 * 1024;
  u16* wqt      = (u16*)(ws);                 // 512 KB bf16
  u16* wkt      = (u16*)(ws + 512 * 1024);
  u16* wvt      = (u16*)(ws + 1024 * 1024);
  u16* wot      = (u16*)(ws + 1536 * 1024);
  float* qb     = (float*)(ws + 2 * MB);      // 8 MB (4096x512 f32)
  float* kb     = (float*)(ws + 10 * MB);     // 8 MB
  float* vb     = (float*)(ws + 18 * MB);     // 8 MB
  float* ctx    = (float*)(ws + 26 * MB);     // 8 MB
  float* bias_m = (float*)(ws + 34 * MB);     // 8 MB
  float* summed = (float*)(ws + 42 * MB);     // 128 KB (64*512 f32, [bh][t])

  int n_edges = in_sizes[3] / 4;

  hipMemsetAsync(bias_m, 0, (size_t)8 * MB, stream);
  transpose_w<<<dim3(16, 16, 4), dim3(32, 8), 0, stream>>>(Wq, Wk, Wv, Wo, wqt, wkt, wvt, wot);
  scatter_bias<<<dim3((n_edges + 255) / 256), 256, 0, stream>>>(ab, be, bsc, bias_m, n_edges);
  gemm_bt<<<dim3(64, 8), 256, 0, stream>>>(states, wqt, qb);
  gemm_bt<<<dim3(64, 8), 256, 0, stream>>>(key_states, wkt, kb);
  gemm_bt<<<dim3(64, 8), 256, 0, stream>>>(key_states, wvt, vb);
  sumk2<<<dim3(8192), 256, 0, stream>>>(kb, summed);
  attn_mfma<<<dim3(512), 256, 0, stream>>>(qb, kb, vb, masks, bias_m, summed, ctx);
  gemm_bt<<<dim3(64, 8), 256, 0, stream>>>(ctx, wot, out);
}